// Round 1
// baseline (221.130 us; speedup 1.0000x reference)
//
#include <hip/hip_runtime.h>
#include <math.h>

#define BB 16
#define HH 8
#define SS 512
#define FF 512
#define DD 64
#define RANKK 12
#define KTOP 51
#define ROWS 8

// monotonic float->uint order mapping (no NaNs in this problem)
__device__ __forceinline__ unsigned f2ord(float x){
  unsigned u = __float_as_uint(x);
  return (u & 0x80000000u) ? ~u : (u | 0x80000000u);
}

// One wave owns one row of 512 values (8 per lane, f = lane*8+j).
// In-place: a[] becomes softmax probabilities of the top-K-masked row
// (mask: value >= exact k-th largest, matching jnp tie semantics).
__device__ __forceinline__ void topk_softmax8(float (&a)[8]){
  unsigned key[8];
#pragma unroll
  for (int j=0;j<8;++j) key[j] = f2ord(a[j]);
  // bit-serial radix select of the KTOP-th largest key:
  // greedy build T from MSB; invariant count(key>=T) >= KTOP.
  unsigned T = 0u;
#pragma unroll
  for (int bit=31; bit>=0; --bit){
    unsigned Tp = T | (1u<<bit);
    int cnt = 0;
#pragma unroll
    for (int j=0;j<8;++j){
      unsigned long long bl = __ballot(key[j] >= Tp);
      cnt += __popcll(bl);
    }
    if (cnt >= KTOP) T = Tp;
  }
  // row max (kept entries include the max)
  float m = a[0];
#pragma unroll
  for (int j=1;j<8;++j) m = fmaxf(m, a[j]);
#pragma unroll
  for (int off=32; off>=1; off>>=1) m = fmaxf(m, __shfl_xor(m, off));
  float sum = 0.f;
#pragma unroll
  for (int j=0;j<8;++j){
    float e = (key[j] >= T) ? expf(a[j]-m) : 0.f;
    a[j] = e; sum += e;
  }
#pragma unroll
  for (int off=32; off>=1; off>>=1) sum += __shfl_xor(sum, off);
  float inv = 1.f/sum;
#pragma unroll
  for (int j=0;j<8;++j) a[j] *= inv;
}

// Kernel 1: score_ln[b*H+h][f] = LN(energy/rms * softplus(temp_h))*w+b
__global__ __launch_bounds__(512) void k_score(const float* __restrict__ values,
    const float* __restrict__ temp, const float* __restrict__ ln_w,
    const float* __restrict__ ln_b, float* __restrict__ score_ln)
{
  const int b = blockIdx.x / HH, h = blockIdx.x % HH;
  const int tid = threadIdx.x, w = tid >> 6, lane = tid & 63;
  __shared__ float s_e[FF];
  __shared__ float ps[8], ps2[8];
  const float* vb = values + ((size_t)b*FF*HH + h)*DD;
  // energy[f] = mean_d v^2 ; wave w covers f in [w*64, w*64+64)
  for (int i=0;i<FF/8;++i){
    int f = w*(FF/8) + i;
    float v = vb[(size_t)f*HH*DD + lane];
    float e = v*v;
#pragma unroll
    for (int off=32; off>=1; off>>=1) e += __shfl_xor(e, off);
    if (lane==0) s_e[f] = e * (1.0f/DD);
  }
  __syncthreads();
  float e = s_e[tid];
  float se = e, se2 = e*e;
#pragma unroll
  for (int off=32; off>=1; off>>=1){ se += __shfl_xor(se, off); se2 += __shfl_xor(se2, off); }
  if (lane==0){ ps[w]=se; ps2[w]=se2; }
  __syncthreads();
  float S1=0.f, S2=0.f;
#pragma unroll
  for (int g=0; g<8; ++g){ S1 += ps[g]; S2 += ps2[g]; }
  float meanE = S1 * (1.0f/FF);
  float rms = fmaxf(sqrtf(meanE), 1e-6f);
  float t = temp[h];
  float gain = (t > 20.f) ? t : log1pf(expf(t));
  float c = gain / rms;                 // score = c * energy
  float mu = c * meanE;
  float var = c*c*(S2*(1.0f/FF) - meanE*meanE);
  float inv = rsqrtf(var + 1e-5f);
  score_ln[(size_t)blockIdx.x*FF + tid] = (c*e - mu)*inv*ln_w[tid] + ln_b[tid];
}

// Kernel 2: A_soft[h*S+s][f] = softmax(topk_mask(alpha*scale)) — shared across b
__global__ __launch_bounds__(512) void k_alpha(const float* __restrict__ alpha,
                                               float* __restrict__ A_soft)
{
  const int w = threadIdx.x >> 6, lane = threadIdx.x & 63;
  const int row = blockIdx.x * ROWS + w;          // h*S+s
  const float SCALE = (float)(1.0/sqrt((double)FF));
  const float* ar = alpha + (size_t)row*FF + lane*8;
  float4 v0 = *(const float4*)ar;
  float4 v1 = *(const float4*)(ar+4);
  float a[8] = {v0.x*SCALE, v0.y*SCALE, v0.z*SCALE, v0.w*SCALE,
                v1.x*SCALE, v1.y*SCALE, v1.z*SCALE, v1.w*SCALE};
  topk_softmax8(a);
  float* orow = A_soft + (size_t)row*FF + lane*8;
  *(float4*)orow     = make_float4(a[0],a[1],a[2],a[3]);
  *(float4*)(orow+4) = make_float4(a[4],a[5],a[6],a[7]);
}

// Kernel 3: per block: 8 rows (one wave each) of one (b,h): build mix in LDS,
// then [8 x 512] @ [512 x 64] with values reused 8x from registers.
template<bool PRE>
__global__ __launch_bounds__(512) void k_main(const float* __restrict__ values,
    const float* __restrict__ alpha, const float* __restrict__ gamma,
    const float* __restrict__ U, const float* __restrict__ V,
    const float* __restrict__ score_ln, const float* __restrict__ A_soft,
    float* __restrict__ out)
{
  const int nwg = BB*HH*(SS/ROWS);                // 8192
  const int bid = (blockIdx.x & 7)*(nwg/8) + (blockIdx.x >> 3); // XCD-chunked swizzle
  const int blocksPerBH = SS / ROWS;              // 64
  const int bh = bid / blocksPerBH;
  const int s0 = (bid % blocksPerBH) * ROWS;
  const int b = bh / HH, h = bh % HH;
  const int tid = threadIdx.x, w = tid >> 6, lane = tid & 63;
  __shared__ float smix[ROWS][FF];                // 16 KB

  // ---- phase 1: wave w builds mix row s0+w ----
  {
    const int s = s0 + w;
    const int f0 = lane*8;
    const float* sr = score_ln + (size_t)bh*FF + f0;
    float4 sv0 = *(const float4*)sr;
    float4 sv1 = *(const float4*)(sr+4);
    const float g = gamma[h*SS + s];
    float dl[8] = {sv0.x+g, sv0.y+g, sv0.z+g, sv0.w+g,
                   sv1.x+g, sv1.y+g, sv1.z+g, sv1.w+g};
    const float* Ur = U + ((size_t)h*SS + s)*RANKK;
    const float* Vh = V + (size_t)h*RANKK*FF + f0;
#pragma unroll
    for (int r=0;r<RANKK;++r){
      float u = Ur[r];
      float4 b0 = *(const float4*)(Vh + r*FF);
      float4 b1 = *(const float4*)(Vh + r*FF + 4);
      dl[0] += u*b0.x; dl[1] += u*b0.y; dl[2] += u*b0.z; dl[3] += u*b0.w;
      dl[4] += u*b1.x; dl[5] += u*b1.y; dl[6] += u*b1.z; dl[7] += u*b1.w;
    }
    topk_softmax8(dl);
    float ap[8];
    if (PRE){
      const float* arow = A_soft + ((size_t)h*SS + s)*FF + f0;
      float4 a0 = *(const float4*)arow;
      float4 a1 = *(const float4*)(arow+4);
      ap[0]=a0.x; ap[1]=a0.y; ap[2]=a0.z; ap[3]=a0.w;
      ap[4]=a1.x; ap[5]=a1.y; ap[6]=a1.z; ap[7]=a1.w;
    } else {
      const float SCALE = (float)(1.0/sqrt((double)FF));
      const float* arow = alpha + ((size_t)h*SS + s)*FF + f0;
      float4 a0 = *(const float4*)arow;
      float4 a1 = *(const float4*)(arow+4);
      ap[0]=a0.x*SCALE; ap[1]=a0.y*SCALE; ap[2]=a0.z*SCALE; ap[3]=a0.w*SCALE;
      ap[4]=a1.x*SCALE; ap[5]=a1.y*SCALE; ap[6]=a1.z*SCALE; ap[7]=a1.w*SCALE;
      topk_softmax8(ap);
    }
    float4 m0 = make_float4(dl[0]+ap[0], dl[1]+ap[1], dl[2]+ap[2], dl[3]+ap[3]);
    float4 m1 = make_float4(dl[4]+ap[4], dl[5]+ap[5], dl[6]+ap[6], dl[7]+ap[7]);
    *(float4*)&smix[w][f0]   = m0;
    *(float4*)&smix[w][f0+4] = m1;
  }
  __syncthreads();

  // ---- phase 2: wave w handles f in [w*64, w*64+64), lane = d ----
  float acc[ROWS] = {0,0,0,0,0,0,0,0};
  {
    const float* vp = values + (size_t)b*FF*HH*DD + (size_t)h*DD + lane;
#pragma unroll
    for (int i=0;i<16;++i){
      const int f0 = w*64 + i*4;
      float x0 = vp[(size_t)(f0+0)*HH*DD];
      float x1 = vp[(size_t)(f0+1)*HH*DD];
      float x2 = vp[(size_t)(f0+2)*HH*DD];
      float x3 = vp[(size_t)(f0+3)*HH*DD];
#pragma unroll
      for (int r=0;r<ROWS;++r){
        float4 m = *(const float4*)&smix[r][f0];   // wave-uniform addr: broadcast
        acc[r] += m.x*x0 + m.y*x1 + m.z*x2 + m.w*x3;
      }
    }
  }
  __syncthreads();

  // ---- phase 3: cross-wave reduce (reuse smix as [8g][8r][64d]) ----
  float* red = &smix[0][0];
#pragma unroll
  for (int r=0;r<ROWS;++r) red[(w*ROWS + r)*64 + lane] = acc[r];
  __syncthreads();
  {
    const int r = w, d = lane;
    float sum = 0.f;
#pragma unroll
    for (int g=0; g<8; ++g) sum += red[(g*ROWS + r)*64 + d];
    out[(((size_t)b*SS + s0 + r)*HH + h)*DD + d] = sum;
  }
}

extern "C" void kernel_launch(void* const* d_in, const int* in_sizes, int n_in,
                              void* d_out, int out_size, void* d_ws, size_t ws_size,
                              hipStream_t stream) {
  const float* values = (const float*)d_in[0];
  const float* alpha  = (const float*)d_in[1];
  const float* temp   = (const float*)d_in[2];
  const float* gamma  = (const float*)d_in[3];
  const float* U      = (const float*)d_in[4];
  const float* V      = (const float*)d_in[5];
  const float* ln_w   = (const float*)d_in[6];
  const float* ln_b   = (const float*)d_in[7];
  float* out = (float*)d_out;

  float* score_ln = (float*)d_ws;                       // B*H*F floats (256 KB)
  float* A_soft   = score_ln + (size_t)BB*HH*FF;        // H*S*F floats (8 MB)
  const size_t need = ((size_t)BB*HH*FF + (size_t)HH*SS*FF)*sizeof(float);
  const bool pre = ws_size >= need;

  hipLaunchKernelGGL(k_score, dim3(BB*HH), dim3(512), 0, stream,
                     values, temp, ln_w, ln_b, score_ln);
  if (pre) {
    hipLaunchKernelGGL(k_alpha, dim3(HH*SS/ROWS), dim3(512), 0, stream, alpha, A_soft);
    hipLaunchKernelGGL((k_main<true>), dim3(BB*HH*(SS/ROWS)), dim3(512), 0, stream,
                       values, alpha, gamma, U, V, score_ln, A_soft, out);
  } else {
    hipLaunchKernelGGL((k_main<false>), dim3(BB*HH*(SS/ROWS)), dim3(512), 0, stream,
                       values, alpha, gamma, U, V, score_ln, A_soft, out);
  }
}